// Round 3
// baseline (283.725 us; speedup 1.0000x reference)
//
#include <hip/hip_runtime.h>

// Problem constants
#define BB    2
#define HN    8
#define NSEQ  2048
#define DIMM  1536
#define DKD   64
#define DVD   192
#define QCOLS 512        // HN*DKD
#define VCOLS 1536       // HN*DVD

typedef short short8 __attribute__((ext_vector_type(8)));
typedef float f32x4  __attribute__((ext_vector_type(4)));
typedef unsigned short ushortT;

static __device__ inline ushortT f2bf(float f) {
    unsigned u = __builtin_bit_cast(unsigned, f);
    u = (u + 0x7FFFu + ((u >> 16) & 1u)) >> 16;
    return (ushortT)u;
}

// async global -> LDS, 16B per lane. LDS dest = wave-uniform base + lane*16.
static __device__ inline void gl_lds16(const ushortT* g, ushortT* l) {
    __builtin_amdgcn_global_load_lds(
        (const __attribute__((address_space(1))) unsigned int*)g,
        (__attribute__((address_space(3))) unsigned int*)l, 16, 0, 0);
}

// HW waitcnt + COMPILER memory fence in one.
#define FENCE_VM0()    asm volatile("s_waitcnt vmcnt(0)" ::: "memory")
#define FENCE_LGKM0()  asm volatile("s_waitcnt lgkmcnt(0)" ::: "memory")
#define FENCE_SOFT()   asm volatile("" ::: "memory")

// ---------------------------------------------------------------------------
// Prep (single launch): region-decoded by blockIdx.x  (unchanged)
// ---------------------------------------------------------------------------
__global__ __launch_bounds__(256)
void prep_kernel(const float* __restrict__ x,
                 const float* __restrict__ Wq, const float* __restrict__ Wk,
                 const float* __restrict__ Wv, const float* __restrict__ Wo,
                 ushortT* __restrict__ xb, ushortT* __restrict__ wqkv,
                 ushortT* __restrict__ wo_t)
{
    __shared__ ushortT tt[32][33];
    const int b = blockIdx.x, tid = threadIdx.x;

    if (b < 3072) {
        const size_t idx = (size_t)b * 256 + tid;
        const float4* p = (const float4*)x + idx * 2;
        const float4 a = p[0], c = p[1];
        short8 v;
        v[0] = f2bf(a.x); v[1] = f2bf(a.y); v[2] = f2bf(a.z); v[3] = f2bf(a.w);
        v[4] = f2bf(c.x); v[5] = f2bf(c.y); v[6] = f2bf(c.z); v[7] = f2bf(c.w);
        *(short8*)(xb + idx * 8) = v;
        return;
    }

    const float* W; ushortT* Wt; int ncols, t;
    if (b < 3840)      { W = Wq; Wt = wqkv;                          ncols = QCOLS; t = b - 3072; }
    else if (b < 4608) { W = Wk; Wt = wqkv + (size_t)QCOLS * DIMM;   ncols = QCOLS; t = b - 3840; }
    else if (b < 6912) { W = Wv; Wt = wqkv + (size_t)2*QCOLS * DIMM; ncols = VCOLS; t = b - 4608; }
    else               { W = Wo; Wt = wo_t;                          ncols = DIMM;  t = b - 6912; }

    const int nbx = ncols >> 5;
    const int c0 = (t % nbx) * 32, k0 = (t / nbx) * 32;
    const int lx = tid & 31, ly = tid >> 5;
    #pragma unroll
    for (int r = 0; r < 4; r++)
        tt[ly + r * 8][lx] = f2bf(W[(size_t)(k0 + ly + r * 8) * ncols + c0 + lx]);
    __syncthreads();
    #pragma unroll
    for (int r = 0; r < 4; r++)
        Wt[(size_t)(c0 + ly + r * 8) * DIMM + k0 + lx] = tt[lx][ly + r * 8];
}

// ---------------------------------------------------------------------------
// GEMM (R8, unchanged): BM=128, BN=64, BK=64; 4 waves, acc[2][4];
// 2-phase LDS double-buffer, one drain barrier per K-step. LDS 48 KB.
// ---------------------------------------------------------------------------
#define NKT (DIMM / 64)   // 24 K-steps

__global__ __launch_bounds__(256)
void gemm_kernel(const ushortT* __restrict__ A, const ushortT* __restrict__ Bt,
                 const float* __restrict__ bo,
                 const float* __restrict__ pos, const float* __restrict__ rcb,
                 ushortT* __restrict__ q_ws, ushortT* __restrict__ k_ws,
                 ushortT* __restrict__ v_ws, float* __restrict__ Cout, int mode)
{
    __shared__ ushortT As[2][128 * 64];   // 2 x 16 KB
    __shared__ ushortT Bs[2][64 * 64];    // 2 x  8 KB

    const int tid  = threadIdx.x;
    const int wave = tid >> 6, lane = tid & 63;
    const int quad = lane >> 4, l15 = lane & 15;
    const int m0 = blockIdx.y * 128, n0 = blockIdx.x * 64;

    const int sl_r = lane >> 3;
    const int sl_c = ((lane & 7) ^ sl_r) * 8;

    const ushortT* Ab = A  + (size_t)m0 * DIMM;
    const ushortT* Bb = Bt + (size_t)n0 * DIMM;

    f32x4 acc[2][4];
    #pragma unroll
    for (int i = 0; i < 2; i++)
        #pragma unroll
        for (int j = 0; j < 4; j++) acc[i][j] = (f32x4){0.f, 0.f, 0.f, 0.f};

    // prologue: stage tile 0 into buf 0
    #pragma unroll
    for (int t = 0; t < 4; t++) {
        const int g = wave * 4 + t;
        gl_lds16(Ab + (size_t)(g * 8 + sl_r) * DIMM + sl_c, &As[0][g * 512]);
    }
    #pragma unroll
    for (int t = 0; t < 2; t++) {
        const int g = wave * 2 + t;
        gl_lds16(Bb + (size_t)(g * 8 + sl_r) * DIMM + sl_c, &Bs[0][g * 512]);
    }
    __syncthreads();

    int cur = 0;
    for (int kt = 0; kt < NKT; kt++) {
        if (kt + 1 < NKT) {
            const int k0 = (kt + 1) * 64;
            #pragma unroll
            for (int t = 0; t < 4; t++) {
                const int g = wave * 4 + t;
                gl_lds16(Ab + (size_t)(g * 8 + sl_r) * DIMM + k0 + sl_c, &As[cur ^ 1][g * 512]);
            }
            #pragma unroll
            for (int t = 0; t < 2; t++) {
                const int g = wave * 2 + t;
                gl_lds16(Bb + (size_t)(g * 8 + sl_r) * DIMM + k0 + sl_c, &Bs[cur ^ 1][g * 512]);
            }
        }

        short8 af[2][2], bf[4][2];
        #pragma unroll
        for (int i = 0; i < 2; i++) {
            const int r = wave * 32 + i * 16 + l15;
            #pragma unroll
            for (int ks = 0; ks < 2; ks++)
                af[i][ks] = *(const short8*)&As[cur][r * 64 + (((ks * 4 + quad) ^ (l15 & 7)) * 8)];
        }
        #pragma unroll
        for (int j = 0; j < 4; j++) {
            const int r = j * 16 + l15;
            #pragma unroll
            for (int ks = 0; ks < 2; ks++)
                bf[j][ks] = *(const short8*)&Bs[cur][r * 64 + (((ks * 4 + quad) ^ (l15 & 7)) * 8)];
        }

        #pragma unroll
        for (int ks = 0; ks < 2; ks++)
            #pragma unroll
            for (int i = 0; i < 2; i++)
                #pragma unroll
                for (int j = 0; j < 4; j++)
                    acc[i][j] = __builtin_amdgcn_mfma_f32_16x16x32_bf16(af[i][ks], bf[j][ks], acc[i][j], 0, 0, 0);

        __syncthreads();
        cur ^= 1;
    }

    #pragma unroll
    for (int i = 0; i < 2; i++) {
        #pragma unroll
        for (int j = 0; j < 4; j++) {
            const int gcol = n0 + j * 16 + l15;
            #pragma unroll
            for (int r = 0; r < 4; r++) {
                const int grow = m0 + wave * 32 + i * 16 + quad * 4 + r;
                const float val = acc[i][j][r];
                if (mode == 1) {
                    Cout[(size_t)grow * DIMM + gcol] = val + bo[gcol];
                } else {
                    const int b = grow >> 11, n = grow & (NSEQ - 1);
                    if (gcol < QCOLS) {
                        const int h = gcol >> 6, d = gcol & 63;
                        q_ws[((size_t)(b * HN + h) * NSEQ + n) * DKD + d] =
                            f2bf(val * 0.125f + pos[((size_t)h * NSEQ + n) * DKD + d] + rcb[h * DKD + d]);
                    } else if (gcol < 2 * QCOLS) {
                        const int c = gcol - QCOLS, h = c >> 6, d = c & 63;
                        k_ws[((size_t)(b * HN + h) * NSEQ + n) * DKD + d] = f2bf(val);
                    } else {
                        const int c = gcol - 2 * QCOLS, h = c / DVD, d = c - h * DVD;
                        v_ws[((size_t)(b * HN + h) * DVD + d) * NSEQ + n] = f2bf(val);   // [b,h,d,key]
                    }
                }
            }
        }
    }
}

// ---------------------------------------------------------------------------
// Flash v3: waves split Q (not keys); SHARED double-buffered K/V staging.
// Grid 512 = 16 bh (XCD-affine) x 32 q-tiles of 64 rows; block = 2 waves,
// wave w owns rows [qt*64 + w*32, +32) and iterates ALL 2048 keys (64
// rounds of 32). Per round the block stages ONE K/V tile (16 KB, 8
// global_load_lds per wave) consumed by BOTH waves -> L2 KV traffic
// halves vs v2c (535 MB vs 1.07 GB). Pipeline: issue stage(t+1) into
// buf^1 -> compute tile t -> __syncthreads() (its vmcnt(0) drain is the
// counted wait; loads had the whole compute phase to land). Key-split
// removal also deletes the cross-wave O/l combine. LDS 37 KB.
// ---------------------------------------------------------------------------
#define PLD2 40
#define SHIFT 20.0f

__global__ __launch_bounds__(128)
void flash_kernel(const ushortT* __restrict__ q_ws, const ushortT* __restrict__ k_ws,
                  const ushortT* __restrict__ v_ws, ushortT* __restrict__ attn)
{
    __shared__ ushortT stg[2][8192];        // per buf: K [0,2048), V^T [2048,8192)
    __shared__ ushortT Pb[2][32 * PLD2];    // per-wave P buffer

    const int tid = threadIdx.x;
    const int wave = tid >> 6, lane = tid & 63;
    const int quad = lane >> 4, l15 = lane & 15;

    const int bh = blockIdx.x & 15;        // XCD-affine: bh's blocks share L2
    const int qt = blockIdx.x >> 4;        // 0..31
    const int n0 = qt * 64 + wave * 32;    // this wave's 32 q-rows
    const int b  = bh >> 3, h = bh & 7;

    const ushortT* kg = k_ws + (size_t)bh * NSEQ * DKD;
    const ushortT* vg = v_ws + (size_t)bh * DVD * NSEQ;   // V^T [d][key]

    ushortT* Pw = Pb[wave];

    // staging source swizzles (same layouts as v2c)
    const int k_r = lane >> 3, k_c = ((lane & 7) ^ (k_r & 7)) * 8;   // K: 8 rows x 8 chunks
    const int v_r = lane >> 2, v_c = ((lane & 3) ^ (v_r & 3)) * 8;   // V: 16 rows x 4 chunks

    // Q A-frags (resident): qf[mt][ks], rows n0 + mt*16 + l15
    short8 qf[2][2];
    #pragma unroll
    for (int mt = 0; mt < 2; mt++)
        #pragma unroll
        for (int ks = 0; ks < 2; ks++)
            qf[mt][ks] = *(const short8*)(q_ws + ((size_t)bh * NSEQ + n0 + mt * 16 + l15) * DKD + ks * 32 + quad * 8);

    f32x4 o[2][12];
    #pragma unroll
    for (int mt = 0; mt < 2; mt++)
        #pragma unroll
        for (int nt = 0; nt < 12; nt++) o[mt][nt] = (f32x4){0.f, 0.f, 0.f, 0.f};

    float l_part[2][4];
    #pragma unroll
    for (int mt = 0; mt < 2; mt++)
        #pragma unroll
        for (int i = 0; i < 4; i++) l_part[mt][i] = 0.f;

    // prologue: stage tile 0 into buf 0 (wave0: K(4)+V(4); wave1: V(8))
    if (wave == 0) {
        #pragma unroll
        for (int t = 0; t < 4; t++)
            gl_lds16(kg + (size_t)(t * 8 + k_r) * DKD + k_c, &stg[0][t * 512]);
        #pragma unroll
        for (int u = 0; u < 4; u++)
            gl_lds16(vg + (size_t)(u * 16 + v_r) * NSEQ + v_c, &stg[0][2048 + u * 512]);
    } else {
        #pragma unroll
        for (int u = 4; u < 12; u++)
            gl_lds16(vg + (size_t)(u * 16 + v_r) * NSEQ + v_c, &stg[0][2048 + u * 512]);
    }
    __syncthreads();   // drains vmcnt(0): tile 0 visible to both waves

    int cur = 0;
    for (int kt0 = 0; kt0 < NSEQ; kt0 += 32) {
        // issue NEXT tile's staging into buf^1 (overlaps with compute below)
        if (kt0 + 32 < NSEQ) {
            const int kn = kt0 + 32;
            if (wave == 0) {
                #pragma unroll
                for (int t = 0; t < 4; t++)
                    gl_lds16(kg + (size_t)(kn + t * 8 + k_r) * DKD + k_c, &stg[cur ^ 1][t * 512]);
                #pragma unroll
                for (int u = 0; u < 4; u++)
                    gl_lds16(vg + (size_t)(u * 16 + v_r) * NSEQ + kn + v_c, &stg[cur ^ 1][2048 + u * 512]);
            } else {
                #pragma unroll
                for (int u = 4; u < 12; u++)
                    gl_lds16(vg + (size_t)(u * 16 + v_r) * NSEQ + kn + v_c, &stg[cur ^ 1][2048 + u * 512]);
            }
        }

        const ushortT* st = stg[cur];

        // ---- S = Q @ K^T ----
        f32x4 s[2][2];
        #pragma unroll
        for (int mt = 0; mt < 2; mt++)
            #pragma unroll
            for (int nt = 0; nt < 2; nt++) s[mt][nt] = (f32x4){0.f, 0.f, 0.f, 0.f};
        #pragma unroll
        for (int ks = 0; ks < 2; ks++)
            #pragma unroll
            for (int nt = 0; nt < 2; nt++) {
                const int key = nt * 16 + l15;
                short8 kf = *(const short8*)&st[key * 64 + (((ks * 4 + quad) ^ (key & 7)) * 8)];
                s[0][nt] = __builtin_amdgcn_mfma_f32_16x16x32_bf16(qf[0][ks], kf, s[0][nt], 0, 0, 0);
                s[1][nt] = __builtin_amdgcn_mfma_f32_16x16x32_bf16(qf[1][ks], kf, s[1][nt], 0, 0, 0);
            }

        // ---- p = exp(s - SHIFT); partial row sums; P C->A via private LDS ----
        #pragma unroll
        for (int mt = 0; mt < 2; mt++)
            #pragma unroll
            for (int nt = 0; nt < 2; nt++)
                #pragma unroll
                for (int i = 0; i < 4; i++) {
                    const float p = __expf(s[mt][nt][i] - SHIFT);
                    s[mt][nt][i] = p;
                    l_part[mt][i] += p;
                    Pw[(mt * 16 + quad * 4 + i) * PLD2 + nt * 16 + l15] = f2bf(p);
                }

        FENCE_SOFT();  // cross-lane P write->read dep is invisible per-lane

        short8 a[2];
        #pragma unroll
        for (int mt = 0; mt < 2; mt++)
            a[mt] = *(const short8*)&Pw[(mt * 16 + l15) * PLD2 + quad * 8];

        // ---- O += P @ V ----
        #pragma unroll
        for (int nt2 = 0; nt2 < 12; nt2++) {
            const int d = nt2 * 16 + l15;
            short8 vf = *(const short8*)&st[2048 + d * 32 + ((quad ^ (d & 3)) * 8)];
            o[0][nt2] = __builtin_amdgcn_mfma_f32_16x16x32_bf16(a[0], vf, o[0][nt2], 0, 0, 0);
            o[1][nt2] = __builtin_amdgcn_mfma_f32_16x16x32_bf16(a[1], vf, o[1][nt2], 0, 0, 0);
        }

        // one barrier per round: drains vmcnt (next tile landed, mine+partner's)
        // and lgkm (all buf reads retired) before buffer swap/overwrite
        __syncthreads();
        cur ^= 1;
    }

    // ---- reduce l over the 16 key-lanes (wave sees ALL keys now) ----
    #pragma unroll
    for (int off = 1; off <= 8; off <<= 1)
        #pragma unroll
        for (int mt = 0; mt < 2; mt++)
            #pragma unroll
            for (int i = 0; i < 4; i++)
                l_part[mt][i] += __shfl_xor(l_part[mt][i], off, 64);

    // ---- each wave normalizes and writes its own 32 rows ----
    float inv[2][4];
    #pragma unroll
    for (int mt = 0; mt < 2; mt++)
        #pragma unroll
        for (int i = 0; i < 4; i++)
            inv[mt][i] = 1.f / l_part[mt][i];
    #pragma unroll
    for (int mt = 0; mt < 2; mt++)
        #pragma unroll
        for (int nt2 = 0; nt2 < 12; nt2++)
            #pragma unroll
            for (int i = 0; i < 4; i++) {
                const int n = n0 + mt * 16 + quad * 4 + i;
                attn[((size_t)b * NSEQ + n) * DIMM + h * DVD + nt2 * 16 + l15] =
                    f2bf(o[mt][nt2][i] * inv[mt][i]);
            }
}

// ---------------------------------------------------------------------------
extern "C" void kernel_launch(void* const* d_in, const int* in_sizes, int n_in,
                              void* d_out, int out_size, void* d_ws, size_t ws_size,
                              hipStream_t stream)
{
    const float* x   = (const float*)d_in[0];
    const float* Wq  = (const float*)d_in[1];
    const float* Wk  = (const float*)d_in[2];
    const float* Wv  = (const float*)d_in[3];
    const float* Wo  = (const float*)d_in[4];
    const float* bo  = (const float*)d_in[5];
    const float* pos = (const float*)d_in[6];
    const float* rcb = (const float*)d_in[7];
    float* out = (float*)d_out;

    ushortT* xb    = (ushortT*)d_ws;                             // 4096*1536
    ushortT* wqkv  = xb    + (size_t)4096 * DIMM;                // 2560*1536
    ushortT* wo_t  = wqkv  + (size_t)(2 * QCOLS + VCOLS) * DIMM; // 1536*1536
    ushortT* q_ws  = wo_t  + (size_t)DIMM * DIMM;
    ushortT* k_ws  = q_ws  + (size_t)BB * HN * NSEQ * DKD;
    ushortT* v_ws  = k_ws  + (size_t)BB * HN * NSEQ * DKD;       // V^T [b,h,d,key]
    ushortT* attnb = v_ws  + (size_t)BB * HN * NSEQ * DVD;       // 4096*1536

    prep_kernel<<<dim3(9216), dim3(256), 0, stream>>>(x, Wq, Wk, Wv, Wo, xb, wqkv, wo_t);

    gemm_kernel<<<dim3(40, 32), dim3(256), 0, stream>>>(xb, wqkv, bo, pos, rcb,
                                                        q_ws, k_ws, v_ws, nullptr, 0);
    flash_kernel<<<dim3(512), dim3(128), 0, stream>>>(q_ws, k_ws, v_ws, attnb);
    gemm_kernel<<<dim3(24, 32), dim3(256), 0, stream>>>(attnb, wo_t, bo, pos, rcb,
                                                        q_ws, k_ws, v_ws, out, 1);
}

// Round 4
// 282.424 us; speedup vs baseline: 1.0046x; 1.0046x over previous
//
#include <hip/hip_runtime.h>

// Problem constants
#define BB    2
#define HN    8
#define NSEQ  2048
#define DIMM  1536
#define DKD   64
#define DVD   192
#define QCOLS 512        // HN*DKD
#define VCOLS 1536       // HN*DVD

typedef short short8 __attribute__((ext_vector_type(8)));
typedef float f32x4  __attribute__((ext_vector_type(4)));
typedef unsigned short ushortT;

static __device__ inline ushortT f2bf(float f) {
    unsigned u = __builtin_bit_cast(unsigned, f);
    u = (u + 0x7FFFu + ((u >> 16) & 1u)) >> 16;
    return (ushortT)u;
}

// RNE f32->bf16 in ONE VALU instr (low half of v_cvt_pk_bf16_f32).
static __device__ inline ushortT f2bf_hw(float f) {
    unsigned r;
    asm("v_cvt_pk_bf16_f32 %0, %1, %1" : "=v"(r) : "v"(f));
    return (ushortT)r;
}

// async global -> LDS, 16B per lane. LDS dest = wave-uniform base + lane*16.
static __device__ inline void gl_lds16(const ushortT* g, ushortT* l) {
    __builtin_amdgcn_global_load_lds(
        (const __attribute__((address_space(1))) unsigned int*)g,
        (__attribute__((address_space(3))) unsigned int*)l, 16, 0, 0);
}

// HW waitcnt + COMPILER memory fence in one.
#define FENCE_VM4()    asm volatile("s_waitcnt vmcnt(4)" ::: "memory")
#define FENCE_LGKM0()  asm volatile("s_waitcnt lgkmcnt(0)" ::: "memory")
#define FENCE_SOFT()   asm volatile("" ::: "memory")

// ---------------------------------------------------------------------------
// Prep (single launch): region-decoded by blockIdx.x  (unchanged)
// ---------------------------------------------------------------------------
__global__ __launch_bounds__(256)
void prep_kernel(const float* __restrict__ x,
                 const float* __restrict__ Wq, const float* __restrict__ Wk,
                 const float* __restrict__ Wv, const float* __restrict__ Wo,
                 ushortT* __restrict__ xb, ushortT* __restrict__ wqkv,
                 ushortT* __restrict__ wo_t)
{
    __shared__ ushortT tt[32][33];
    const int b = blockIdx.x, tid = threadIdx.x;

    if (b < 3072) {
        const size_t idx = (size_t)b * 256 + tid;
        const float4* p = (const float4*)x + idx * 2;
        const float4 a = p[0], c = p[1];
        short8 v;
        v[0] = f2bf(a.x); v[1] = f2bf(a.y); v[2] = f2bf(a.z); v[3] = f2bf(a.w);
        v[4] = f2bf(c.x); v[5] = f2bf(c.y); v[6] = f2bf(c.z); v[7] = f2bf(c.w);
        *(short8*)(xb + idx * 8) = v;
        return;
    }

    const float* W; ushortT* Wt; int ncols, t;
    if (b < 3840)      { W = Wq; Wt = wqkv;                          ncols = QCOLS; t = b - 3072; }
    else if (b < 4608) { W = Wk; Wt = wqkv + (size_t)QCOLS * DIMM;   ncols = QCOLS; t = b - 3840; }
    else if (b < 6912) { W = Wv; Wt = wqkv + (size_t)2*QCOLS * DIMM; ncols = VCOLS; t = b - 4608; }
    else               { W = Wo; Wt = wo_t;                          ncols = DIMM;  t = b - 6912; }

    const int nbx = ncols >> 5;
    const int c0 = (t % nbx) * 32, k0 = (t / nbx) * 32;
    const int lx = tid & 31, ly = tid >> 5;
    #pragma unroll
    for (int r = 0; r < 4; r++)
        tt[ly + r * 8][lx] = f2bf(W[(size_t)(k0 + ly + r * 8) * ncols + c0 + lx]);
    __syncthreads();
    #pragma unroll
    for (int r = 0; r < 4; r++)
        Wt[(size_t)(c0 + ly + r * 8) * DIMM + k0 + lx] = tt[lx][ly + r * 8];
}

// ---------------------------------------------------------------------------
// GEMM (unchanged from R2/R8): BM=128, BN=64, BK=64; 4 waves, acc[2][4];
// 2-phase LDS double-buffer, one drain barrier per K-step. LDS 48 KB.
// ---------------------------------------------------------------------------
#define NKT (DIMM / 64)   // 24 K-steps

__global__ __launch_bounds__(256)
void gemm_kernel(const ushortT* __restrict__ A, const ushortT* __restrict__ Bt,
                 const float* __restrict__ bo,
                 const float* __restrict__ pos, const float* __restrict__ rcb,
                 ushortT* __restrict__ q_ws, ushortT* __restrict__ k_ws,
                 ushortT* __restrict__ v_ws, float* __restrict__ Cout, int mode)
{
    __shared__ ushortT As[2][128 * 64];   // 2 x 16 KB
    __shared__ ushortT Bs[2][64 * 64];    // 2 x  8 KB

    const int tid  = threadIdx.x;
    const int wave = tid >> 6, lane = tid & 63;
    const int quad = lane >> 4, l15 = lane & 15;
    const int m0 = blockIdx.y * 128, n0 = blockIdx.x * 64;

    const int sl_r = lane >> 3;
    const int sl_c = ((lane & 7) ^ sl_r) * 8;

    const ushortT* Ab = A  + (size_t)m0 * DIMM;
    const ushortT* Bb = Bt + (size_t)n0 * DIMM;

    f32x4 acc[2][4];
    #pragma unroll
    for (int i = 0; i < 2; i++)
        #pragma unroll
        for (int j = 0; j < 4; j++) acc[i][j] = (f32x4){0.f, 0.f, 0.f, 0.f};

    // prologue: stage tile 0 into buf 0
    #pragma unroll
    for (int t = 0; t < 4; t++) {
        const int g = wave * 4 + t;
        gl_lds16(Ab + (size_t)(g * 8 + sl_r) * DIMM + sl_c, &As[0][g * 512]);
    }
    #pragma unroll
    for (int t = 0; t < 2; t++) {
        const int g = wave * 2 + t;
        gl_lds16(Bb + (size_t)(g * 8 + sl_r) * DIMM + sl_c, &Bs[0][g * 512]);
    }
    __syncthreads();

    int cur = 0;
    for (int kt = 0; kt < NKT; kt++) {
        if (kt + 1 < NKT) {
            const int k0 = (kt + 1) * 64;
            #pragma unroll
            for (int t = 0; t < 4; t++) {
                const int g = wave * 4 + t;
                gl_lds16(Ab + (size_t)(g * 8 + sl_r) * DIMM + k0 + sl_c, &As[cur ^ 1][g * 512]);
            }
            #pragma unroll
            for (int t = 0; t < 2; t++) {
                const int g = wave * 2 + t;
                gl_lds16(Bb + (size_t)(g * 8 + sl_r) * DIMM + k0 + sl_c, &Bs[cur ^ 1][g * 512]);
            }
        }

        short8 af[2][2], bf[4][2];
        #pragma unroll
        for (int i = 0; i < 2; i++) {
            const int r = wave * 32 + i * 16 + l15;
            #pragma unroll
            for (int ks = 0; ks < 2; ks++)
                af[i][ks] = *(const short8*)&As[cur][r * 64 + (((ks * 4 + quad) ^ (l15 & 7)) * 8)];
        }
        #pragma unroll
        for (int j = 0; j < 4; j++) {
            const int r = j * 16 + l15;
            #pragma unroll
            for (int ks = 0; ks < 2; ks++)
                bf[j][ks] = *(const short8*)&Bs[cur][r * 64 + (((ks * 4 + quad) ^ (l15 & 7)) * 8)];
        }

        #pragma unroll
        for (int ks = 0; ks < 2; ks++)
            #pragma unroll
            for (int i = 0; i < 2; i++)
                #pragma unroll
                for (int j = 0; j < 4; j++)
                    acc[i][j] = __builtin_amdgcn_mfma_f32_16x16x32_bf16(af[i][ks], bf[j][ks], acc[i][j], 0, 0, 0);

        __syncthreads();
        cur ^= 1;
    }

    #pragma unroll
    for (int i = 0; i < 2; i++) {
        #pragma unroll
        for (int j = 0; j < 4; j++) {
            const int gcol = n0 + j * 16 + l15;
            #pragma unroll
            for (int r = 0; r < 4; r++) {
                const int grow = m0 + wave * 32 + i * 16 + quad * 4 + r;
                const float val = acc[i][j][r];
                if (mode == 1) {
                    Cout[(size_t)grow * DIMM + gcol] = val + bo[gcol];
                } else {
                    const int b = grow >> 11, n = grow & (NSEQ - 1);
                    if (gcol < QCOLS) {
                        const int h = gcol >> 6, d = gcol & 63;
                        q_ws[((size_t)(b * HN + h) * NSEQ + n) * DKD + d] =
                            f2bf(val * 0.125f + pos[((size_t)h * NSEQ + n) * DKD + d] + rcb[h * DKD + d]);
                    } else if (gcol < 2 * QCOLS) {
                        const int c = gcol - QCOLS, h = c >> 6, d = c & 63;
                        k_ws[((size_t)(b * HN + h) * NSEQ + n) * DKD + d] = f2bf(val);
                    } else {
                        const int c = gcol - 2 * QCOLS, h = c / DVD, d = c - h * DVD;
                        v_ws[((size_t)(b * HN + h) * DVD + d) * NSEQ + n] = f2bf(val);   // [b,h,d,key]
                    }
                }
            }
        }
    }
}

// ---------------------------------------------------------------------------
// Flash v4: v2c structure (grid 1024 = 16 bh x 64 q-tiles of 32 rows; 2
// waves/block, wave w owns keys [w*1024,+1024), private staging, barrier-
// free) with three critical-path fixes:
//  1. K-frags prefetched ONE ROUND AHEAD into REGISTERS (per-lane 16B
//     loads == the exact B-frag); no K LDS, no exposed K wait. FENCE_SOFT
//     pins K-reg loads AFTER the 12 V gl_lds so FENCE_VM4 counts right.
//  2. PLD2=36: P-store quads hit 4 disjoint bank octets (was 4-way
//     conflicted at 40).
//  3. f2bf via v_cvt_pk_bf16_f32 (1 instr vs 4) in the softmax.
// Per round: lgkm0 -> stage V(12 gl_lds) -> issue K(t+1) regs -> QK from
// regs -> softmax/P -> vmcnt(4) (V landed, K-next in flight) -> PV.
// LDS 28.5 KB -> 4 blocks/CU (grid-limited), 8 waves/CU.
// ---------------------------------------------------------------------------
#define PLD2 36
#define SHIFT 20.0f

__global__ __launch_bounds__(128)
void flash_kernel(const ushortT* __restrict__ q_ws, const ushortT* __restrict__ k_ws,
                  const ushortT* __restrict__ v_ws, ushortT* __restrict__ attn)
{
    // [0,12288): per-wave V^T staging (wave*6144 shorts = 12 KB each)
    // [12288,14592): P buffers (wave*32*PLD2); reused for O/l exchange at end
    __shared__ ushortT lds[2 * 6144 + 2 * 32 * PLD2];

    const int tid = threadIdx.x;
    const int wave = tid >> 6, lane = tid & 63;
    const int quad = lane >> 4, l15 = lane & 15;

    const int bh = blockIdx.x & 15;        // XCD-affine: bh's blocks share L2
    const int qt = blockIdx.x >> 4;
    const int n0 = qt * 32;
    const int b  = bh >> 3, h = bh & 7;

    const ushortT* kg = k_ws + (size_t)bh * NSEQ * DKD + (size_t)(wave * 1024) * DKD;
    const ushortT* vg = v_ws + (size_t)bh * DVD * NSEQ + wave * 1024;

    ushortT* st = lds + wave * 6144;           // V^T tile
    ushortT* Pw = lds + 12288 + wave * (32 * PLD2);

    // V staging source swizzle (16 rows x 4 chunks per gl_lds)
    const int v_r = lane >> 2, v_c = ((lane & 3) ^ (v_r & 3)) * 8;

    // Q A-frags (resident): qf[mt][ks], rows n0 + mt*16 + l15
    short8 qf[2][2];
    #pragma unroll
    for (int mt = 0; mt < 2; mt++)
        #pragma unroll
        for (int ks = 0; ks < 2; ks++)
            qf[mt][ks] = *(const short8*)(q_ws + ((size_t)bh * NSEQ + n0 + mt * 16 + l15) * DKD + ks * 32 + quad * 8);

    // K B-frag register base: lane (l15,quad) reads K[key=kt+nt*16+l15][ks*32+quad*8 ..+7]
    const ushortT* kb = kg + (size_t)l15 * DKD + quad * 8;

    short8 kf[2][2];
    #pragma unroll
    for (int ks = 0; ks < 2; ks++)
        #pragma unroll
        for (int nt = 0; nt < 2; nt++)
            kf[ks][nt] = *(const short8*)(kb + (size_t)(nt * 16) * DKD + ks * 32);

    f32x4 o[2][12];
    #pragma unroll
    for (int mt = 0; mt < 2; mt++)
        #pragma unroll
        for (int nt = 0; nt < 12; nt++) o[mt][nt] = (f32x4){0.f, 0.f, 0.f, 0.f};

    float l_part[2][4];
    #pragma unroll
    for (int mt = 0; mt < 2; mt++)
        #pragma unroll
        for (int i = 0; i < 4; i++) l_part[mt][i] = 0.f;

    for (int kt0 = 0; kt0 < 1024; kt0 += 32) {
        FENCE_LGKM0();   // prior-round V/P ds ops retired before overwrite

        #pragma unroll
        for (int u = 0; u < 12; u++)      // V^T tile: 192 d x 32 keys = 12 KB
            gl_lds16(vg + (size_t)(u * 16 + v_r) * NSEQ + kt0 + v_c, st + u * 512);

        FENCE_SOFT();   // pin K-reg loads AFTER all V gl_lds (vmcnt ordering)

        // prefetch K(t+1) into registers (wraps to 0 on last round; discarded)
        const int ktn = (kt0 + 32) & 1023;
        short8 kn[2][2];
        #pragma unroll
        for (int ks = 0; ks < 2; ks++)
            #pragma unroll
            for (int nt = 0; nt < 2; nt++)
                kn[ks][nt] = *(const short8*)(kb + (size_t)(ktn + nt * 16) * DKD + ks * 32);

        // ---- S = Q @ K^T (K frags already in registers; no wait) ----
        f32x4 s[2][2];
        #pragma unroll
        for (int mt = 0; mt < 2; mt++)
            #pragma unroll
            for (int nt = 0; nt < 2; nt++) s[mt][nt] = (f32x4){0.f, 0.f, 0.f, 0.f};
        #pragma unroll
        for (int ks = 0; ks < 2; ks++)
            #pragma unroll
            for (int nt = 0; nt < 2; nt++) {
                s[0][nt] = __builtin_amdgcn_mfma_f32_16x16x32_bf16(qf[0][ks], kf[ks][nt], s[0][nt], 0, 0, 0);
                s[1][nt] = __builtin_amdgcn_mfma_f32_16x16x32_bf16(qf[1][ks], kf[ks][nt], s[1][nt], 0, 0, 0);
            }

        // ---- p = exp(s - SHIFT); partial row sums; P C->A via private LDS ----
        #pragma unroll
        for (int mt = 0; mt < 2; mt++)
            #pragma unroll
            for (int nt = 0; nt < 2; nt++)
                #pragma unroll
                for (int i = 0; i < 4; i++) {
                    const float p = __expf(s[mt][nt][i] - SHIFT);
                    l_part[mt][i] += p;
                    Pw[(mt * 16 + quad * 4 + i) * PLD2 + nt * 16 + l15] = f2bf_hw(p);
                }

        FENCE_SOFT();  // cross-lane P write->read dep is invisible per-lane

        short8 a[2];
        #pragma unroll
        for (int mt = 0; mt < 2; mt++)
            a[mt] = *(const short8*)&Pw[(mt * 16 + l15) * PLD2 + quad * 8];

        FENCE_VM4();   // 12 V landed; 4 K-prefetch loads still in flight

        // ---- O += P @ V ----
        #pragma unroll
        for (int nt2 = 0; nt2 < 12; nt2++) {
            const int d = nt2 * 16 + l15;
            short8 vf = *(const short8*)&st[d * 32 + ((quad ^ (d & 3)) * 8)];
            o[0][nt2] = __builtin_amdgcn_mfma_f32_16x16x32_bf16(a[0], vf, o[0][nt2], 0, 0, 0);
            o[1][nt2] = __builtin_amdgcn_mfma_f32_16x16x32_bf16(a[1], vf, o[1][nt2], 0, 0, 0);
        }

        // rotate K prefetch
        #pragma unroll
        for (int ks = 0; ks < 2; ks++)
            #pragma unroll
            for (int nt = 0; nt < 2; nt++)
                kf[ks][nt] = kn[ks][nt];
    }

    // ---- reduce l over the 16 key-lanes ----
    #pragma unroll
    for (int off = 1; off <= 8; off <<= 1)
        #pragma unroll
        for (int mt = 0; mt < 2; mt++)
            #pragma unroll
            for (int i = 0; i < 4; i++)
                l_part[mt][i] += __shfl_xor(l_part[mt][i], off, 64);

    // ---- combine key-half partials in LDS; wave 0 finalizes ----
    __syncthreads();
    float* ox = (float*)lds;              // 96 slots x 64 lanes = 24576 B
    float* lx = (float*)(lds + 12288);    // 8 slots x 64 lanes = 2048 B
    if (wave == 1) {
        #pragma unroll
        for (int mt = 0; mt < 2; mt++)
            #pragma unroll
            for (int nt2 = 0; nt2 < 12; nt2++)
                #pragma unroll
                for (int i = 0; i < 4; i++)
                    ox[(((mt * 12 + nt2) * 4 + i) * 64) + lane] = o[mt][nt2][i];
        #pragma unroll
        for (int mt = 0; mt < 2; mt++)
            #pragma unroll
            for (int i = 0; i < 4; i++)
                lx[(mt * 4 + i) * 64 + lane] = l_part[mt][i];
    }
    __syncthreads();
    if (wave == 0) {
        float inv[2][4];
        #pragma unroll
        for (int mt = 0; mt < 2; mt++)
            #pragma unroll
            for (int i = 0; i < 4; i++)
                inv[mt][i] = 1.f / (l_part[mt][i] + lx[(mt * 4 + i) * 64 + lane]);
        #pragma unroll
        for (int mt = 0; mt < 2; mt++)
            #pragma unroll
            for (int nt2 = 0; nt2 < 12; nt2++)
                #pragma unroll
                for (int i = 0; i < 4; i++) {
                    const float v = o[mt][nt2][i] + ox[(((mt * 12 + nt2) * 4 + i) * 64) + lane];
                    const int n = n0 + mt * 16 + quad * 4 + i;
                    attn[((size_t)b * NSEQ + n) * DIMM + h * DVD + nt2 * 16 + l15] =
                        f2bf(v * inv[mt][i]);
                }
    }
}

// ---------------------------------------------------------------------------
extern "C" void kernel_launch(void* const* d_in, const int* in_sizes, int n_in,
                              void* d_out, int out_size, void* d_ws, size_t ws_size,
                              hipStream_t stream)
{
    const float* x   = (const float*)d_in[0];
    const float* Wq  = (const float*)d_in[1];
    const float* Wk  = (const float*)d_in[2];
    const float* Wv  = (const float*)d_in[3];
    const float* Wo  = (const float*)d_in[4];
    const float* bo  = (const float*)d_in[5];
    const float* pos = (const float*)d_in[6];
    const float* rcb = (const float*)d_in[7];
    float* out = (float*)d_out;

    ushortT* xb    = (ushortT*)d_ws;                             // 4096*1536
    ushortT* wqkv  = xb    + (size_t)4096 * DIMM;                // 2560*1536
    ushortT* wo_t  = wqkv  + (size_t)(2 * QCOLS + VCOLS) * DIMM; // 1536*1536
    ushortT* q_ws  = wo_t  + (size_t)DIMM * DIMM;
    ushortT* k_ws  = q_ws  + (size_t)BB * HN * NSEQ * DKD;
    ushortT* v_ws  = k_ws  + (size_t)BB * HN * NSEQ * DKD;       // V^T [b,h,d,key]
    ushortT* attnb = v_ws  + (size_t)BB * HN * NSEQ * DVD;       // 4096*1536

    prep_kernel<<<dim3(9216), dim3(256), 0, stream>>>(x, Wq, Wk, Wv, Wo, xb, wqkv, wo_t);

    gemm_kernel<<<dim3(40, 32), dim3(256), 0, stream>>>(xb, wqkv, bo, pos, rcb,
                                                        q_ws, k_ws, v_ws, nullptr, 0);
    flash_kernel<<<dim3(1024), dim3(128), 0, stream>>>(q_ws, k_ws, v_ws, attnb);
    gemm_kernel<<<dim3(24, 32), dim3(256), 0, stream>>>(attnb, wo_t, bo, pos, rcb,
                                                        q_ws, k_ws, v_ws, out, 1);
}

// Round 5
// 264.358 us; speedup vs baseline: 1.0733x; 1.0683x over previous
//
#include <hip/hip_runtime.h>

// Problem constants
#define BB    2
#define HN    8
#define NSEQ  2048
#define DIMM  1536
#define DKD   64
#define DVD   192
#define QCOLS 512        // HN*DKD
#define VCOLS 1536       // HN*DVD

typedef short short8 __attribute__((ext_vector_type(8)));
typedef float f32x4  __attribute__((ext_vector_type(4)));
typedef unsigned short ushortT;

static __device__ inline ushortT f2bf(float f) {
    unsigned u = __builtin_bit_cast(unsigned, f);
    u = (u + 0x7FFFu + ((u >> 16) & 1u)) >> 16;
    return (ushortT)u;
}

// async global -> LDS, 16B per lane. LDS dest = wave-uniform base + lane*16.
static __device__ inline void gl_lds16(const ushortT* g, ushortT* l) {
    __builtin_amdgcn_global_load_lds(
        (const __attribute__((address_space(1))) unsigned int*)g,
        (__attribute__((address_space(3))) unsigned int*)l, 16, 0, 0);
}

// HW waitcnt + COMPILER memory fence in one.
#define FENCE_VM0()    asm volatile("s_waitcnt vmcnt(0)" ::: "memory")
#define FENCE_VM12()   asm volatile("s_waitcnt vmcnt(12)" ::: "memory")
#define FENCE_LGKM0()  asm volatile("s_waitcnt lgkmcnt(0)" ::: "memory")
#define FENCE_SOFT()   asm volatile("" ::: "memory")

// ---------------------------------------------------------------------------
// Prep (single launch): region-decoded by blockIdx.x  (unchanged)
// ---------------------------------------------------------------------------
__global__ __launch_bounds__(256)
void prep_kernel(const float* __restrict__ x,
                 const float* __restrict__ Wq, const float* __restrict__ Wk,
                 const float* __restrict__ Wv, const float* __restrict__ Wo,
                 ushortT* __restrict__ xb, ushortT* __restrict__ wqkv,
                 ushortT* __restrict__ wo_t)
{
    __shared__ ushortT tt[32][33];
    const int b = blockIdx.x, tid = threadIdx.x;

    if (b < 3072) {
        const size_t idx = (size_t)b * 256 + tid;
        const float4* p = (const float4*)x + idx * 2;
        const float4 a = p[0], c = p[1];
        short8 v;
        v[0] = f2bf(a.x); v[1] = f2bf(a.y); v[2] = f2bf(a.z); v[3] = f2bf(a.w);
        v[4] = f2bf(c.x); v[5] = f2bf(c.y); v[6] = f2bf(c.z); v[7] = f2bf(c.w);
        *(short8*)(xb + idx * 8) = v;
        return;
    }

    const float* W; ushortT* Wt; int ncols, t;
    if (b < 3840)      { W = Wq; Wt = wqkv;                          ncols = QCOLS; t = b - 3072; }
    else if (b < 4608) { W = Wk; Wt = wqkv + (size_t)QCOLS * DIMM;   ncols = QCOLS; t = b - 3840; }
    else if (b < 6912) { W = Wv; Wt = wqkv + (size_t)2*QCOLS * DIMM; ncols = VCOLS; t = b - 4608; }
    else               { W = Wo; Wt = wo_t;                          ncols = DIMM;  t = b - 6912; }

    const int nbx = ncols >> 5;
    const int c0 = (t % nbx) * 32, k0 = (t / nbx) * 32;
    const int lx = tid & 31, ly = tid >> 5;
    #pragma unroll
    for (int r = 0; r < 4; r++)
        tt[ly + r * 8][lx] = f2bf(W[(size_t)(k0 + ly + r * 8) * ncols + c0 + lx]);
    __syncthreads();
    #pragma unroll
    for (int r = 0; r < 4; r++)
        Wt[(size_t)(c0 + ly + r * 8) * DIMM + k0 + lx] = tt[lx][ly + r * 8];
}

// ---------------------------------------------------------------------------
// GEMM (R2 dbuf, unchanged except the v_ws key-slot permutation):
// BM=128, BN=64, BK=64; 4 waves, acc[2][4]; 2-phase LDS double-buffer,
// one drain barrier per K-step. LDS 48 KB.
// v_ws key-slot permutation: within each 32-key group, key n -> slot
// 2*(n&15) | ((n>>4)&1). MFMA sums over k, so permuting k-slots is
// identity-preserving as long as flash's P-columns use the SAME order —
// which its packed P-store does (slot 2*l15+nt for key nt*16+l15).
// ---------------------------------------------------------------------------
#define NKT (DIMM / 64)   // 24 K-steps

__global__ __launch_bounds__(256)
void gemm_kernel(const ushortT* __restrict__ A, const ushortT* __restrict__ Bt,
                 const float* __restrict__ bo,
                 const float* __restrict__ pos, const float* __restrict__ rcb,
                 ushortT* __restrict__ q_ws, ushortT* __restrict__ k_ws,
                 ushortT* __restrict__ v_ws, float* __restrict__ Cout, int mode)
{
    __shared__ ushortT As[2][128 * 64];   // 2 x 16 KB
    __shared__ ushortT Bs[2][64 * 64];    // 2 x  8 KB

    const int tid  = threadIdx.x;
    const int wave = tid >> 6, lane = tid & 63;
    const int quad = lane >> 4, l15 = lane & 15;
    const int m0 = blockIdx.y * 128, n0 = blockIdx.x * 64;

    const int sl_r = lane >> 3;
    const int sl_c = ((lane & 7) ^ sl_r) * 8;

    const ushortT* Ab = A  + (size_t)m0 * DIMM;
    const ushortT* Bb = Bt + (size_t)n0 * DIMM;

    f32x4 acc[2][4];
    #pragma unroll
    for (int i = 0; i < 2; i++)
        #pragma unroll
        for (int j = 0; j < 4; j++) acc[i][j] = (f32x4){0.f, 0.f, 0.f, 0.f};

    // prologue: stage tile 0 into buf 0
    #pragma unroll
    for (int t = 0; t < 4; t++) {
        const int g = wave * 4 + t;
        gl_lds16(Ab + (size_t)(g * 8 + sl_r) * DIMM + sl_c, &As[0][g * 512]);
    }
    #pragma unroll
    for (int t = 0; t < 2; t++) {
        const int g = wave * 2 + t;
        gl_lds16(Bb + (size_t)(g * 8 + sl_r) * DIMM + sl_c, &Bs[0][g * 512]);
    }
    __syncthreads();

    int cur = 0;
    for (int kt = 0; kt < NKT; kt++) {
        if (kt + 1 < NKT) {
            const int k0 = (kt + 1) * 64;
            #pragma unroll
            for (int t = 0; t < 4; t++) {
                const int g = wave * 4 + t;
                gl_lds16(Ab + (size_t)(g * 8 + sl_r) * DIMM + k0 + sl_c, &As[cur ^ 1][g * 512]);
            }
            #pragma unroll
            for (int t = 0; t < 2; t++) {
                const int g = wave * 2 + t;
                gl_lds16(Bb + (size_t)(g * 8 + sl_r) * DIMM + k0 + sl_c, &Bs[cur ^ 1][g * 512]);
            }
        }

        short8 af[2][2], bf[4][2];
        #pragma unroll
        for (int i = 0; i < 2; i++) {
            const int r = wave * 32 + i * 16 + l15;
            #pragma unroll
            for (int ks = 0; ks < 2; ks++)
                af[i][ks] = *(const short8*)&As[cur][r * 64 + (((ks * 4 + quad) ^ (l15 & 7)) * 8)];
        }
        #pragma unroll
        for (int j = 0; j < 4; j++) {
            const int r = j * 16 + l15;
            #pragma unroll
            for (int ks = 0; ks < 2; ks++)
                bf[j][ks] = *(const short8*)&Bs[cur][r * 64 + (((ks * 4 + quad) ^ (l15 & 7)) * 8)];
        }

        #pragma unroll
        for (int ks = 0; ks < 2; ks++)
            #pragma unroll
            for (int i = 0; i < 2; i++)
                #pragma unroll
                for (int j = 0; j < 4; j++)
                    acc[i][j] = __builtin_amdgcn_mfma_f32_16x16x32_bf16(af[i][ks], bf[j][ks], acc[i][j], 0, 0, 0);

        __syncthreads();
        cur ^= 1;
    }

    #pragma unroll
    for (int i = 0; i < 2; i++) {
        #pragma unroll
        for (int j = 0; j < 4; j++) {
            const int gcol = n0 + j * 16 + l15;
            #pragma unroll
            for (int r = 0; r < 4; r++) {
                const int grow = m0 + wave * 32 + i * 16 + quad * 4 + r;
                const float val = acc[i][j][r];
                if (mode == 1) {
                    Cout[(size_t)grow * DIMM + gcol] = val + bo[gcol];
                } else {
                    const int b = grow >> 11, n = grow & (NSEQ - 1);
                    if (gcol < QCOLS) {
                        const int h = gcol >> 6, d = gcol & 63;
                        q_ws[((size_t)(b * HN + h) * NSEQ + n) * DKD + d] =
                            f2bf(val * 0.125f + pos[((size_t)h * NSEQ + n) * DKD + d] + rcb[h * DKD + d]);
                    } else if (gcol < 2 * QCOLS) {
                        const int c = gcol - QCOLS, h = c >> 6, d = c & 63;
                        k_ws[((size_t)(b * HN + h) * NSEQ + n) * DKD + d] = f2bf(val);
                    } else {
                        const int c = gcol - 2 * QCOLS, h = c / DVD, d = c - h * DVD;
                        // interleaved key-slot within each 32-key group
                        const int p = (n & ~31) | (((n & 15) << 1) | ((n >> 4) & 1));
                        v_ws[((size_t)(b * HN + h) * DVD + d) * NSEQ + p] = f2bf(val);   // [b,h,d,slot]
                    }
                }
            }
        }
    }
}

// ---------------------------------------------------------------------------
// Flash v2c (verbatim R0/R2 structure) + packed P-store.
// Grid 1024 = 16 bh (XCD-affine) x 64 q-tiles of 32 rows. Block = 2 waves.
// Wave w: keys [w*1024, +1024), KT=32, 32 rounds, PRIVATE 16KB K/V staging;
// per-wave self-sync: lgkm0 -> stage K(4)+V(12) -> vmcnt(12) -> QK/softmax/P
// -> vmcnt(0) -> PV. Key-half partials combined via one LDS exchange at end.
// 37.9KB LDS -> 4 blocks/CU = 8 waves/CU.
// Packed P: lane holds BOTH nt=0/nt=1 values of each P-row (keys l15 and
// l15+16); with v_ws's interleaved key slots (2*l15+nt), they pack into one
// v_cvt_pk_bf16_f32 + one ds_write_b32: 16 b16 writes -> 8 b32 writes,
// ~64 f2bf VALU ops -> 8 cvt_pk. b32 writes at PLD2=40 are 2 lanes/bank.
// ---------------------------------------------------------------------------
#define PLD2 40
#define SHIFT 20.0f

__global__ __launch_bounds__(128)
void flash_kernel(const ushortT* __restrict__ q_ws, const ushortT* __restrict__ k_ws,
                  const ushortT* __restrict__ v_ws, ushortT* __restrict__ attn)
{
    // [0,16384): per-wave staging (wave*8192: K 2048 shorts, V 6144 shorts)
    // [16384,18944): P buffers (wave*32*PLD2); reused for l exchange at end
    __shared__ ushortT lds[16384 + 2 * 32 * PLD2];

    const int tid = threadIdx.x;
    const int wave = tid >> 6, lane = tid & 63;
    const int quad = lane >> 4, l15 = lane & 15;

    const int bh = blockIdx.x & 15;        // XCD-affine: bh's blocks share L2
    const int qt = blockIdx.x >> 4;
    const int n0 = qt * 32;
    const int b  = bh >> 3, h = bh & 7;

    const ushortT* kg = k_ws + (size_t)bh * NSEQ * DKD + (size_t)(wave * 1024) * DKD;
    const ushortT* vg = v_ws + (size_t)bh * DVD * NSEQ + wave * 1024;

    ushortT* st = lds + wave * 8192;           // K at [0,2048), V at [2048,8192)
    ushortT* Pw = lds + 16384 + wave * (32 * PLD2);

    // staging source swizzles
    const int k_r = lane >> 3, k_c = ((lane & 7) ^ (k_r & 7)) * 8;   // K: 8 rows x 8 chunks
    const int v_r = lane >> 2, v_c = ((lane & 3) ^ (v_r & 3)) * 8;   // V: 16 rows x 4 chunks

    // Q A-frags (resident): qf[mt][ks], rows n0 + mt*16 + l15
    short8 qf[2][2];
    #pragma unroll
    for (int mt = 0; mt < 2; mt++)
        #pragma unroll
        for (int ks = 0; ks < 2; ks++)
            qf[mt][ks] = *(const short8*)(q_ws + ((size_t)bh * NSEQ + n0 + mt * 16 + l15) * DKD + ks * 32 + quad * 8);

    f32x4 o[2][12];
    #pragma unroll
    for (int mt = 0; mt < 2; mt++)
        #pragma unroll
        for (int nt = 0; nt < 12; nt++) o[mt][nt] = (f32x4){0.f, 0.f, 0.f, 0.f};

    float l_part[2][4];
    #pragma unroll
    for (int mt = 0; mt < 2; mt++)
        #pragma unroll
        for (int i = 0; i < 4; i++) l_part[mt][i] = 0.f;

    for (int kt0 = 0; kt0 < 1024; kt0 += 32) {
        // all prior ds_reads on this wave's buffers must be retired
        FENCE_LGKM0();

        #pragma unroll
        for (int t = 0; t < 4; t++)       // K tile: 32 keys x 64 d = 4 KB
            gl_lds16(kg + (size_t)(kt0 + t * 8 + k_r) * DKD + k_c, st + t * 512);
        #pragma unroll
        for (int u = 0; u < 12; u++)      // V^T tile: 192 d x 32 key-slots = 12 KB
            gl_lds16(vg + (size_t)(u * 16 + v_r) * NSEQ + kt0 + v_c, st + 2048 + u * 512);

        FENCE_VM12();  // 4 oldest (K) landed; V still in flight

        // ---- S = Q @ K^T ----
        f32x4 s[2][2];
        #pragma unroll
        for (int mt = 0; mt < 2; mt++)
            #pragma unroll
            for (int nt = 0; nt < 2; nt++) s[mt][nt] = (f32x4){0.f, 0.f, 0.f, 0.f};
        #pragma unroll
        for (int ks = 0; ks < 2; ks++)
            #pragma unroll
            for (int nt = 0; nt < 2; nt++) {
                const int key = nt * 16 + l15;
                short8 kf = *(const short8*)&st[key * 64 + (((ks * 4 + quad) ^ (key & 7)) * 8)];
                s[0][nt] = __builtin_amdgcn_mfma_f32_16x16x32_bf16(qf[0][ks], kf, s[0][nt], 0, 0, 0);
                s[1][nt] = __builtin_amdgcn_mfma_f32_16x16x32_bf16(qf[1][ks], kf, s[1][nt], 0, 0, 0);
            }

        // ---- p = exp(s - SHIFT); row-sum partials; PACKED P store ----
        // lane holds keys l15 (nt=0) and l15+16 (nt=1) of row mt*16+quad*4+i;
        // interleaved slots (2*l15, 2*l15+1) -> one cvt_pk + one b32 write.
        #pragma unroll
        for (int mt = 0; mt < 2; mt++)
            #pragma unroll
            for (int i = 0; i < 4; i++) {
                const float p0 = __expf(s[mt][0][i] - SHIFT);
                const float p1 = __expf(s[mt][1][i] - SHIFT);
                l_part[mt][i] += p0 + p1;
                unsigned pk;
                asm("v_cvt_pk_bf16_f32 %0, %1, %2" : "=v"(pk) : "v"(p0), "v"(p1));
                *(unsigned*)&Pw[(mt * 16 + quad * 4 + i) * PLD2 + 2 * l15] = pk;
            }

        FENCE_SOFT();  // cross-lane P write->read dep is invisible per-lane

        short8 a[2];
        #pragma unroll
        for (int mt = 0; mt < 2; mt++)
            a[mt] = *(const short8*)&Pw[(mt * 16 + l15) * PLD2 + quad * 8];

        FENCE_VM0();   // V landed

        // ---- O += P @ V (k-slots permuted identically on both operands) ----
        #pragma unroll
        for (int nt2 = 0; nt2 < 12; nt2++) {
            const int d = nt2 * 16 + l15;
            short8 vf = *(const short8*)&st[2048 + d * 32 + ((quad ^ (d & 3)) * 8)];
            o[0][nt2] = __builtin_amdgcn_mfma_f32_16x16x32_bf16(a[0], vf, o[0][nt2], 0, 0, 0);
            o[1][nt2] = __builtin_amdgcn_mfma_f32_16x16x32_bf16(a[1], vf, o[1][nt2], 0, 0, 0);
        }
    }

    // ---- reduce l over the 16 key-lanes ----
    #pragma unroll
    for (int off = 1; off <= 8; off <<= 1)
        #pragma unroll
        for (int mt = 0; mt < 2; mt++)
            #pragma unroll
            for (int i = 0; i < 4; i++)
                l_part[mt][i] += __shfl_xor(l_part[mt][i], off, 64);

    // ---- combine key-half partials in LDS; wave 0 finalizes ----
    __syncthreads();
    float* ox = (float*)lds;              // 96 slots x 64 lanes = 24.6 KB
    float* lx = (float*)(lds + 16384);    // 8 slots x 64 lanes = 2 KB
    if (wave == 1) {
        #pragma unroll
        for (int mt = 0; mt < 2; mt++)
            #pragma unroll
            for (int nt2 = 0; nt2 < 12; nt2++)
                #pragma unroll
                for (int i = 0; i < 4; i++)
                    ox[(((mt * 12 + nt2) * 4 + i) * 64) + lane] = o[mt][nt2][i];
        #pragma unroll
        for (int mt = 0; mt < 2; mt++)
            #pragma unroll
            for (int i = 0; i < 4; i++)
                lx[(mt * 4 + i) * 64 + lane] = l_part[mt][i];
    }
    __syncthreads();
    if (wave == 0) {
        float inv[2][4];
        #pragma unroll
        for (int mt = 0; mt < 2; mt++)
            #pragma unroll
            for (int i = 0; i < 4; i++)
                inv[mt][i] = 1.f / (l_part[mt][i] + lx[(mt * 4 + i) * 64 + lane]);
        #pragma unroll
        for (int mt = 0; mt < 2; mt++)
            #pragma unroll
            for (int nt2 = 0; nt2 < 12; nt2++)
                #pragma unroll
                for (int i = 0; i < 4; i++) {
                    const float v = o[mt][nt2][i] + ox[(((mt * 12 + nt2) * 4 + i) * 64) + lane];
                    const int n = n0 + mt * 16 + quad * 4 + i;
                    attn[((size_t)b * NSEQ + n) * DIMM + h * DVD + nt2 * 16 + l15] =
                        f2bf(v * inv[mt][i]);
                }
    }
}

// ---------------------------------------------------------------------------
extern "C" void kernel_launch(void* const* d_in, const int* in_sizes, int n_in,
                              void* d_out, int out_size, void* d_ws, size_t ws_size,
                              hipStream_t stream)
{
    const float* x   = (const float*)d_in[0];
    const float* Wq  = (const float*)d_in[1];
    const float* Wk  = (const float*)d_in[2];
    const float* Wv  = (const float*)d_in[3];
    const float* Wo  = (const float*)d_in[4];
    const float* bo  = (const float*)d_in[5];
    const float* pos = (const float*)d_in[6];
    const float* rcb = (const float*)d_in[7];
    float* out = (float*)d_out;

    ushortT* xb    = (ushortT*)d_ws;                             // 4096*1536
    ushortT* wqkv  = xb    + (size_t)4096 * DIMM;                // 2560*1536
    ushortT* wo_t  = wqkv  + (size_t)(2 * QCOLS + VCOLS) * DIMM; // 1536*1536
    ushortT* q_ws  = wo_t  + (size_t)DIMM * DIMM;
    ushortT* k_ws  = q_ws  + (size_t)BB * HN * NSEQ * DKD;
    ushortT* v_ws  = k_ws  + (size_t)BB * HN * NSEQ * DKD;       // V^T [b,h,d,slot]
    ushortT* attnb = v_ws  + (size_t)BB * HN * NSEQ * DVD;       // 4096*1536

    prep_kernel<<<dim3(9216), dim3(256), 0, stream>>>(x, Wq, Wk, Wv, Wo, xb, wqkv, wo_t);

    gemm_kernel<<<dim3(40, 32), dim3(256), 0, stream>>>(xb, wqkv, bo, pos, rcb,
                                                        q_ws, k_ws, v_ws, nullptr, 0);
    flash_kernel<<<dim3(1024), dim3(128), 0, stream>>>(q_ws, k_ws, v_ws, attnb);
    gemm_kernel<<<dim3(24, 32), dim3(256), 0, stream>>>(attnb, wo_t, bo, pos, rcb,
                                                        q_ws, k_ws, v_ws, out, 1);
}